// Round 10
// baseline (941.221 us; speedup 1.0000x reference)
//
#include <hip/hip_runtime.h>
#include <hip/hip_fp16.h>
#include <math.h>

#define NNODES 100000
#define NEDGES 1600000
#define NGRAPH 256
#define NCONV  3
#define TBL    2048
#define NB1    98          // ceil(100000/1024)
#define R_MIN_ 1.0f
#define R_MAX_ 6.0f

typedef float v2f __attribute__((ext_vector_type(2)));

__device__ __forceinline__ float softplus_f(float x){
  return fmaxf(x, 0.f) + __logf(1.f + __expf(-fabsf(x)));
}
__device__ __forceinline__ float sigmoid_f(float x){
  return __builtin_amdgcn_rcpf(1.f + __expf(-x));
}
__device__ __forceinline__ void fma4(float4& a, float s, const float4 w){
  a.x = fmaf(s, w.x, a.x); a.y = fmaf(s, w.y, a.y);
  a.z = fmaf(s, w.z, a.z); a.w = fmaf(s, w.w, a.w);
}

// ---------------- init ----------------
__global__ void k_init(int* deg, float* gsum, int* gcnt){
  int i = blockIdx.x*256 + threadIdx.x;
  if (i < NNODES) deg[i] = 0;
  if (i < NGRAPH){ gsum[i] = 0.f; gcnt[i] = 0; }
}

// ---------------- embedding gather ----------------
__global__ void k_embed(const int* __restrict__ numbers, const float* __restrict__ embed,
                        float* __restrict__ x){
  int i = blockIdx.x*256 + threadIdx.x;
  if (i >= NNODES*64) return;
  int n = i >> 6, c = i & 63;
  x[i] = embed[numbers[n]*64 + c];
}

// ---------------- CSR build ----------------
// 4 edges per thread: 4 independent atomics in flight (latency MLP)
__global__ void k_hist(const int* __restrict__ src, int* deg){
  int e0 = (blockIdx.x*256 + threadIdx.x)*4;
  if (e0 >= NEDGES) return;
  int4 s = *(const int4*)(src + e0);
  atomicAdd(&deg[s.x], 1); atomicAdd(&deg[s.y], 1);
  atomicAdd(&deg[s.z], 1); atomicAdd(&deg[s.w], 1);
}

__global__ void k_scan1(const int* __restrict__ deg, int* __restrict__ offs, int* __restrict__ bsum){
  __shared__ int s[1024];
  int n = blockIdx.x*1024 + threadIdx.x;
  int v = (n < NNODES) ? deg[n] : 0;
  s[threadIdx.x] = v;
  __syncthreads();
  for (int d = 1; d < 1024; d <<= 1){
    int t = (threadIdx.x >= d) ? s[threadIdx.x - d] : 0;
    __syncthreads();
    s[threadIdx.x] += t;
    __syncthreads();
  }
  int incl = s[threadIdx.x];
  if (n < NNODES) offs[n] = incl - v;
  if (threadIdx.x == 1023) bsum[blockIdx.x] = incl;
}

__global__ void k_scan2(const int* __restrict__ bsum, int* __restrict__ bbase, int* __restrict__ offs){
  if (blockIdx.x == 0 && threadIdx.x == 0){
    int run = 0;
    for (int b = 0; b < NB1; b++){ int t = bsum[b]; bbase[b] = run; run += t; }
    offs[NNODES] = NEDGES;
  }
}

__global__ void k_scan3(int* __restrict__ offs, const int* __restrict__ bbase, int* __restrict__ cur){
  int n = blockIdx.x*256 + threadIdx.x;
  if (n < NNODES){
    int o = offs[n] + bbase[n >> 10];
    offs[n] = o;
    cur[n]  = o;
  }
}

// pack edge: (tgt, idx<<16 | half(frac)); 4 edges per thread for atomic MLP
__global__ void k_scatter(const int* __restrict__ src, const int* __restrict__ tgt,
                          const float* __restrict__ elen, int* cur,
                          int2* __restrict__ ep){
  int e0 = (blockIdx.x*256 + threadIdx.x)*4;
  if (e0 >= NEDGES) return;
  int4   s4 = *(const int4*)(src + e0);
  int4   t4 = *(const int4*)(tgt + e0);
  float4 l4 = *(const float4*)(elen + e0);
  int ss[4] = {s4.x, s4.y, s4.z, s4.w};
  int tt[4] = {t4.x, t4.y, t4.z, t4.w};
  float ll[4] = {l4.x, l4.y, l4.z, l4.w};
  int pos[4];
  #pragma unroll
  for (int i = 0; i < 4; i++) pos[i] = atomicAdd(&cur[ss[i]], 1);
  #pragma unroll
  for (int i = 0; i < 4; i++){
    float key = (ll[i] - R_MIN_) * ((float)(TBL-1)/(R_MAX_-R_MIN_));
    key = fminf(fmaxf(key, 0.f), (float)(TBL-1) - 1e-3f);
    int idx = (int)key;
    float fr = key - (float)idx;
    unsigned short fh = __half_as_ushort(__float2half_rn(fr));
    ep[pos[i]] = make_int2(tt[i], (idx << 16) | (int)fh);
  }
}

// ---------------- Gaussian table, written directly in interleaved Gt2 form ----------------
// Gt2 row r, lane l: float4 (G[r][2l], G[r][2l+1], G[r+1][2l], G[r+1][2l+1])
__global__ void k_gauss(const float* __restrict__ Wf, const float* __restrict__ bf,
                        const float* __restrict__ Ws, const float* __restrict__ bs,
                        float* __restrict__ Gt2){
  __shared__ float attr[64];
  int bi = blockIdx.x;
  int i = bi / TBL, r = bi % TBL;
  int t = threadIdx.x;
  float d = R_MIN_ + (R_MAX_-R_MIN_) * (float)r / (float)(TBL-1);
  if (t < 64){
    float cj = 1.f + 5.f * (float)t / 63.f;
    float u = (d - cj) * (64.f/5.f);
    attr[t] = __expf(-0.5f*u*u);
  }
  __syncthreads();
  int c = t >> 1;
  int side = t & 1;
  const float* W = (side ? Ws : Wf) + i*192*64 + 128*64 + c;
  float acc = (side ? bs : bf)[i*64 + c];
  #pragma unroll 8
  for (int j = 0; j < 64; j++) acc = fmaf(attr[j], W[j*64], acc);
  float* base = Gt2 + (size_t)i*TBL*256;
  base[(size_t)r*256 + 4*c + side] = acc;                 // g0 slot of row r
  if (r > 0) base[(size_t)(r-1)*256 + 4*c + 2 + side] = acc;  // g1 slot of row r-1
}

// ---------------- Wcat pack ----------------
__global__ void k_wcat(const float* __restrict__ Wf, const float* __restrict__ Ws,
                       float* __restrict__ Wcat){
  int idx = blockIdx.x*256 + threadIdx.x;
  if (idx >= 3*64*256) return;
  int i = idx / (64*256);
  int rem = idx % (64*256);
  int k = rem / 256, c = rem % 256;
  float v;
  if (c < 128){
    int p = c >> 1; bool ss = (c & 1);
    v = (ss ? Ws : Wf)[i*192*64 + k*64 + p];
  } else {
    int p = (c-128) >> 1; bool ss = (c & 1);
    v = (ss ? Ws : Wf)[i*192*64 + (64+k)*64 + p];
  }
  Wcat[i*64*256 + k*256 + c] = v;
}

// ---------------- node transform: 32 nodes x 256 cols; p and q stored fp16 ----------------
__global__ void k_ntrans(const float* __restrict__ x, const float* __restrict__ Wc,
                         __half2* __restrict__ pqh){
  __shared__ float xs[32*64];       // 8 KB
  int n0 = blockIdx.x * 32;         // 3125 blocks exact
  int t = threadIdx.x;              // 256
  ((float4*)xs)[t]       = ((const float4*)(x + (size_t)n0*64))[t];
  ((float4*)xs)[t + 256] = ((const float4*)(x + (size_t)n0*64))[t + 256];
  __syncthreads();
  int cg = t & 63, ng = t >> 6;     // 64 col-groups x 4 cols; 4 node-groups x 8 nodes
  float4 acc[8];
  #pragma unroll
  for (int i = 0; i < 8; i++) acc[i] = make_float4(0.f,0.f,0.f,0.f);
  const float* wp = Wc + 4*cg;
  const float* xp = xs + ng*8*64;
  #pragma unroll 2
  for (int k = 0; k < 64; k += 4){
    float4 w0 = *(const float4*)(wp + (k+0)*256);
    float4 w1 = *(const float4*)(wp + (k+1)*256);
    float4 w2 = *(const float4*)(wp + (k+2)*256);
    float4 w3 = *(const float4*)(wp + (k+3)*256);
    #pragma unroll
    for (int nn = 0; nn < 8; nn++){
      float4 xv = *(const float4*)(xp + nn*64 + k);
      fma4(acc[nn], xv.x, w0); fma4(acc[nn], xv.y, w1);
      fma4(acc[nn], xv.z, w2); fma4(acc[nn], xv.w, w3);
    }
  }
  #pragma unroll
  for (int nn = 0; nn < 8; nn++){
    int node = n0 + ng*8 + nn;
    __half2 h0 = __float22half2_rn(make_float2(acc[nn].x, acc[nn].y));
    __half2 h1 = __float22half2_rn(make_float2(acc[nn].z, acc[nn].w));
    __half2* dst = pqh + (size_t)node*128 + 2*cg;
    dst[0] = h0; dst[1] = h1;
  }
}

// ---------------- edge pass: wave per node, metadata-pipelined ----------------
__global__ void k_edge(const __half2* __restrict__ pqh,
                       const int* __restrict__ offs, const int2* __restrict__ ep,
                       const float* __restrict__ Gt2, const float* __restrict__ lng,
                       const float* __restrict__ lnb, float* __restrict__ x){
  int wid  = (blockIdx.x*256 + threadIdx.x) >> 6;
  int lane = threadIdx.x & 63;
  int n = wid;
  int j0 = __builtin_amdgcn_readfirstlane(offs[n]);
  int j1 = __builtin_amdgcn_readfirstlane(offs[n+1]);
  int nfull = (j1 - j0) >> 3;
  int2 eb[8];
  if (nfull > 0){
    #pragma unroll
    for (int i = 0; i < 8; i++) eb[i] = ep[j0 + i];
  }
  float2 pp = __half22float2(pqh[(size_t)n*128 + lane]);
  v2f pv; pv.x = pp.x; pv.y = pp.y;
  float acc = 0.f;
  int u = j0;
  for (int b = 0; b < nfull; b++){
    int tgv[8], idxv[8]; float frv[8];
    #pragma unroll
    for (int i = 0; i < 8; i++){
      tgv[i]  = eb[i].x;
      idxv[i] = ((unsigned)eb[i].y) >> 16;
      frv[i]  = __half2float(__ushort_as_half((unsigned short)(eb[i].y & 0xffff)));
    }
    __half2 qr[8]; float4 gv[8];
    #pragma unroll
    for (int i = 0; i < 8; i++){
      qr[i] = pqh[(size_t)tgv[i]*128 + 64 + lane];
      gv[i] = *(const float4*)(Gt2 + (size_t)idxv[i]*256 + 4*lane);
    }
    if (b + 1 < nfull){
      #pragma unroll
      for (int i = 0; i < 8; i++) eb[i] = ep[u + 8 + i];
    }
    #pragma unroll
    for (int i = 0; i < 8; i++){
      float2 qf = __half22float2(qr[i]);
      v2f qv; qv.x = qf.x; qv.y = qf.y;
      v2f g0; g0.x = gv[i].x; g0.y = gv[i].y;
      v2f g1; g1.x = gv[i].z; g1.y = gv[i].w;
      v2f fr2; fr2.x = frv[i]; fr2.y = frv[i];
      v2f z = pv + qv + g0 + fr2*(g1 - g0);
      acc = fmaf(sigmoid_f(z.x), softplus_f(z.y), acc);
    }
    u += 8;
  }
  for (; u < j1; u++){
    int2 e = ep[u];
    int tg = e.x;
    int idx = ((unsigned)e.y) >> 16;
    float fr0 = __half2float(__ushort_as_half((unsigned short)(e.y & 0xffff)));
    float2 qf = __half22float2(pqh[(size_t)tg*128 + 64 + lane]);
    float4 gvv = *(const float4*)(Gt2 + (size_t)idx*256 + 4*lane);
    float rf = fmaf(fr0, gvv.z - gvv.x, gvv.x);
    float rs = fmaf(fr0, gvv.w - gvv.y, gvv.y);
    acc = fmaf(sigmoid_f(pp.x + qf.x + rf), softplus_f(pp.y + qf.y + rs), acc);
  }
  float s1 = acc, s2 = acc*acc;
  #pragma unroll
  for (int o = 32; o > 0; o >>= 1){ s1 += __shfl_xor(s1, o, 64); s2 += __shfl_xor(s2, o, 64); }
  float mu  = s1 * (1.f/64.f);
  float var = s2 * (1.f/64.f) - mu*mu;
  float inv = rsqrtf(fmaxf(var, 0.f) + 1e-5f);
  float y = (acc - mu) * inv * lng[lane] + lnb[lane];
  x[(size_t)n*64 + lane] += y;
}

// ---------------- fused head with K=8 register-prefetched weights ----------------
__global__ void k_head(const float* __restrict__ x,
                       const float* __restrict__ W1, const float* __restrict__ b1,
                       const float* __restrict__ g1, const float* __restrict__ bt1,
                       const float* __restrict__ W2, const float* __restrict__ b2,
                       const float* __restrict__ g2, const float* __restrict__ bt2,
                       const float* __restrict__ Wout, const int* __restrict__ batch,
                       float* gsum, int* gcnt){
  __shared__ float xs[32*64];       // 8 KB
  __shared__ float hs[32*128];      // 16 KB
  __shared__ float es[32];
  int n0 = blockIdx.x * 32;         // 3125 blocks
  int t = threadIdx.x;              // 256
  ((float4*)xs)[t]       = ((const float4*)(x + (size_t)n0*64))[t];
  ((float4*)xs)[t + 256] = ((const float4*)(x + (size_t)n0*64))[t + 256];
  __syncthreads();
  int cg = t & 31, ng = t >> 5;     // 32 col-groups x 4 cols; 8 node-groups x 4 nodes

  // ---- layer 1: 64 -> 128, LN, softplus, into hs ----
  {
    float4 acc[4];
    #pragma unroll
    for (int i = 0; i < 4; i++) acc[i] = make_float4(0.f,0.f,0.f,0.f);
    const float* wp = W1 + 4*cg;
    const float* xp = xs + ng*4*64;
    float4 w[8];
    #pragma unroll
    for (int j = 0; j < 8; j++) w[j] = *(const float4*)(wp + j*128);
    for (int k = 0; k < 64; k += 8){
      float4 wn[8];
      int kn = (k + 8 < 64) ? k + 8 : 0;
      #pragma unroll
      for (int j = 0; j < 8; j++) wn[j] = *(const float4*)(wp + (kn+j)*128);
      #pragma unroll
      for (int h = 0; h < 2; h++){
        #pragma unroll
        for (int nn = 0; nn < 4; nn++){
          float4 xv = *(const float4*)(xp + nn*64 + k + h*4);
          fma4(acc[nn], xv.x, w[h*4+0]); fma4(acc[nn], xv.y, w[h*4+1]);
          fma4(acc[nn], xv.z, w[h*4+2]); fma4(acc[nn], xv.w, w[h*4+3]);
        }
      }
      #pragma unroll
      for (int j = 0; j < 8; j++) w[j] = wn[j];
    }
    float4 bv  = *(const float4*)(b1  + 4*cg);
    float4 gv  = *(const float4*)(g1  + 4*cg);
    float4 btv = *(const float4*)(bt1 + 4*cg);
    #pragma unroll
    for (int nn = 0; nn < 4; nn++){
      float4 v = acc[nn];
      v.x += bv.x; v.y += bv.y; v.z += bv.z; v.w += bv.w;
      float s1 = v.x + v.y + v.z + v.w;
      float s2 = v.x*v.x + v.y*v.y + v.z*v.z + v.w*v.w;
      #pragma unroll
      for (int o = 16; o > 0; o >>= 1){ s1 += __shfl_xor(s1, o, 64); s2 += __shfl_xor(s2, o, 64); }
      float mu  = s1 * (1.f/128.f);
      float var = s2 * (1.f/128.f) - mu*mu;
      float inv = rsqrtf(fmaxf(var, 0.f) + 1e-5f);
      float4 o4;
      o4.x = softplus_f((v.x - mu)*inv*gv.x + btv.x);
      o4.y = softplus_f((v.y - mu)*inv*gv.y + btv.y);
      o4.z = softplus_f((v.z - mu)*inv*gv.z + btv.z);
      o4.w = softplus_f((v.w - mu)*inv*gv.w + btv.w);
      *(float4*)(hs + (ng*4 + nn)*128 + 4*cg) = o4;
    }
  }
  __syncthreads();

  // ---- layer 2: 128 -> 128, LN, softplus, proj -> per-node energy in es ----
  {
    float4 acc[4];
    #pragma unroll
    for (int i = 0; i < 4; i++) acc[i] = make_float4(0.f,0.f,0.f,0.f);
    const float* wp = W2 + 4*cg;
    const float* hp = hs + ng*4*128;
    float4 w[8];
    #pragma unroll
    for (int j = 0; j < 8; j++) w[j] = *(const float4*)(wp + j*128);
    for (int k = 0; k < 128; k += 8){
      float4 wn[8];
      int kn = (k + 8 < 128) ? k + 8 : 0;
      #pragma unroll
      for (int j = 0; j < 8; j++) wn[j] = *(const float4*)(wp + (kn+j)*128);
      #pragma unroll
      for (int h = 0; h < 2; h++){
        #pragma unroll
        for (int nn = 0; nn < 4; nn++){
          float4 hv = *(const float4*)(hp + nn*128 + k + h*4);
          fma4(acc[nn], hv.x, w[h*4+0]); fma4(acc[nn], hv.y, w[h*4+1]);
          fma4(acc[nn], hv.z, w[h*4+2]); fma4(acc[nn], hv.w, w[h*4+3]);
        }
      }
      #pragma unroll
      for (int j = 0; j < 8; j++) w[j] = wn[j];
    }
    float4 bv  = *(const float4*)(b2  + 4*cg);
    float4 gv  = *(const float4*)(g2  + 4*cg);
    float4 btv = *(const float4*)(bt2 + 4*cg);
    float4 wo  = *(const float4*)(Wout + 4*cg);
    #pragma unroll
    for (int nn = 0; nn < 4; nn++){
      float4 v = acc[nn];
      v.x += bv.x; v.y += bv.y; v.z += bv.z; v.w += bv.w;
      float s1 = v.x + v.y + v.z + v.w;
      float s2 = v.x*v.x + v.y*v.y + v.z*v.z + v.w*v.w;
      #pragma unroll
      for (int o = 16; o > 0; o >>= 1){ s1 += __shfl_xor(s1, o, 64); s2 += __shfl_xor(s2, o, 64); }
      float mu  = s1 * (1.f/128.f);
      float var = s2 * (1.f/128.f) - mu*mu;
      float inv = rsqrtf(fmaxf(var, 0.f) + 1e-5f);
      float ev = softplus_f((v.x - mu)*inv*gv.x + btv.x) * wo.x
               + softplus_f((v.y - mu)*inv*gv.y + btv.y) * wo.y
               + softplus_f((v.z - mu)*inv*gv.z + btv.z) * wo.z
               + softplus_f((v.w - mu)*inv*gv.w + btv.w) * wo.w;
      #pragma unroll
      for (int o = 16; o > 0; o >>= 1) ev += __shfl_xor(ev, o, 64);
      if (cg == 0) es[ng*4 + nn] = ev;
    }
  }
  __syncthreads();

  // ---- segmented reduction over the sorted 32-node tile ----
  if (t < 32){
    int node = n0 + t;
    int g = batch[node];
    bool head = (t == 0) || (batch[node-1] != g);
    if (head){
      float s = 0.f; int c = 0;
      int j = t;
      while (j < 32 && batch[n0+j] == g){ s += es[j]; c++; j++; }
      atomicAdd(&gsum[g], s);
      atomicAdd(&gcnt[g], c);
    }
  }
}

// ---------------- final ----------------
__global__ void k_final(const float* __restrict__ gsum, const int* __restrict__ gcnt,
                        const float* __restrict__ bout, float* __restrict__ out){
  int g = threadIdx.x;
  if (g < NGRAPH)
    out[g] = gsum[g] / fmaxf((float)gcnt[g], 1.f) + bout[0];
}

extern "C" void kernel_launch(void* const* d_in, const int* in_sizes, int n_in,
                              void* d_out, int out_size, void* d_ws, size_t ws_size,
                              hipStream_t stream){
  const int*   numbers = (const int*)d_in[0];
  const int*   eidx    = (const int*)d_in[1];
  const float* elen    = (const float*)d_in[2];
  const int*   batch   = (const int*)d_in[3];
  const float* embed   = (const float*)d_in[4];
  const float* Wf      = (const float*)d_in[5];
  const float* bf      = (const float*)d_in[6];
  const float* Ws      = (const float*)d_in[7];
  const float* bs      = (const float*)d_in[8];
  const float* lng     = (const float*)d_in[9];
  const float* lnb     = (const float*)d_in[10];
  const float* W1      = (const float*)d_in[11];
  const float* b1      = (const float*)d_in[12];
  const float* g1      = (const float*)d_in[13];
  const float* bt1     = (const float*)d_in[14];
  const float* W2      = (const float*)d_in[15];
  const float* b2      = (const float*)d_in[16];
  const float* g2      = (const float*)d_in[17];
  const float* bt2     = (const float*)d_in[18];
  const float* Wout    = (const float*)d_in[19];
  const float* bout    = (const float*)d_in[20];
  const int* src = eidx;
  const int* tgt = eidx + NEDGES;

  float*   x    = (float*)d_ws;                          // N*64 f32
  __half2* pqh  = (__half2*)(x + (size_t)NNODES*64);     // N*128 half2
  float*   Gt2  = (float*)(pqh + (size_t)NNODES*128);    // 3*TBL*256 f32
  float*   Wcat = Gt2  + (size_t)3*TBL*256;              // 3*64*256
  int2*    ep   = (int2*)(Wcat + (size_t)3*64*256);      // E int2
  int*     offs = (int*)(ep + NEDGES);                   // N+1
  int*     cur  = offs + NNODES + 1;                     // N
  int*     deg  = cur  + NNODES;                         // N
  int*     bsum = deg  + NNODES;                         // 128
  int*     bbase= bsum + 128;                            // 128
  float*   gsum = (float*)(bbase + 128);                 // 256
  int*     gcnt = (int*)(gsum + NGRAPH);                 // 256
  float*   out  = (float*)d_out;

  k_init  <<<(NNODES+255)/256, 256, 0, stream>>>(deg, gsum, gcnt);
  k_embed <<<(NNODES*64+255)/256, 256, 0, stream>>>(numbers, embed, x);

  k_hist   <<<(NEDGES/4+255)/256, 256, 0, stream>>>(src, deg);
  k_scan1  <<<NB1, 1024, 0, stream>>>(deg, offs, bsum);
  k_scan2  <<<1, 64, 0, stream>>>(bsum, bbase, offs);
  k_scan3  <<<(NNODES+255)/256, 256, 0, stream>>>(offs, bbase, cur);
  k_scatter<<<(NEDGES/4+255)/256, 256, 0, stream>>>(src, tgt, elen, cur, ep);

  k_gauss <<<3*TBL, 128, 0, stream>>>(Wf, bf, Ws, bs, Gt2);
  k_wcat  <<<(3*64*256+255)/256, 256, 0, stream>>>(Wf, Ws, Wcat);

  for (int i = 0; i < NCONV; i++){
    k_ntrans<<<NNODES/32, 256, 0, stream>>>(x, Wcat + (size_t)i*64*256, pqh);
    k_edge  <<<NNODES/4, 256, 0, stream>>>(pqh, offs, ep,
                                           Gt2 + (size_t)i*TBL*256,
                                           lng + i*64, lnb + i*64, x);
  }

  k_head<<<NNODES/32, 256, 0, stream>>>(x, W1, b1, g1, bt1,
                                        W2, b2, g2, bt2, Wout, batch, gsum, gcnt);
  k_final<<<1, 256, 0, stream>>>(gsum, gcnt, bout, out);
}

// Round 11
// 869.976 us; speedup vs baseline: 1.0819x; 1.0819x over previous
//
#include <hip/hip_runtime.h>
#include <hip/hip_fp16.h>
#include <math.h>

#define NNODES 100000
#define NEDGES 1600000
#define NGRAPH 256
#define NCONV  3
#define TBL    2048
#define NB1    98          // ceil(100000/1024)
#define CHUNK  512
#define NCHUNK 196         // ceil(100000/512)
#define R_MIN_ 1.0f
#define R_MAX_ 6.0f

typedef float v2f __attribute__((ext_vector_type(2)));

__device__ __forceinline__ float softplus_f(float x){
  return fmaxf(x, 0.f) + __logf(1.f + __expf(-fabsf(x)));
}
__device__ __forceinline__ float sigmoid_f(float x){
  return __builtin_amdgcn_rcpf(1.f + __expf(-x));
}
__device__ __forceinline__ void fma4(float4& a, float s, const float4 w){
  a.x = fmaf(s, w.x, a.x); a.y = fmaf(s, w.y, a.y);
  a.z = fmaf(s, w.z, a.z); a.w = fmaf(s, w.w, a.w);
}

// ---------------- init ----------------
__global__ void k_init(int* deg, float* gsum, int* gcnt){
  int i = blockIdx.x*256 + threadIdx.x;
  if (i < NNODES) deg[i] = 0;
  if (i < NGRAPH){ gsum[i] = 0.f; gcnt[i] = 0; }
}

// ---------------- embedding gather ----------------
__global__ void k_embed(const int* __restrict__ numbers, const float* __restrict__ embed,
                        float* __restrict__ x){
  int i = blockIdx.x*256 + threadIdx.x;
  if (i >= NNODES*64) return;
  int n = i >> 6, c = i & 63;
  x[i] = embed[numbers[n]*64 + c];
}

// ---------------- CSR build ----------------
__global__ void k_hist(const int* __restrict__ src, int* deg){
  int e = blockIdx.x*256 + threadIdx.x;
  if (e < NEDGES) atomicAdd(&deg[src[e]], 1);
}

__global__ void k_scan1(const int* __restrict__ deg, int* __restrict__ offs, int* __restrict__ bsum){
  __shared__ int s[1024];
  int n = blockIdx.x*1024 + threadIdx.x;
  int v = (n < NNODES) ? deg[n] : 0;
  s[threadIdx.x] = v;
  __syncthreads();
  for (int d = 1; d < 1024; d <<= 1){
    int t = (threadIdx.x >= d) ? s[threadIdx.x - d] : 0;
    __syncthreads();
    s[threadIdx.x] += t;
    __syncthreads();
  }
  int incl = s[threadIdx.x];
  if (n < NNODES) offs[n] = incl - v;
  if (threadIdx.x == 1023) bsum[blockIdx.x] = incl;
}

__global__ void k_scan2(const int* __restrict__ bsum, int* __restrict__ bbase, int* __restrict__ offs){
  if (blockIdx.x == 0 && threadIdx.x == 0){
    int run = 0;
    for (int b = 0; b < NB1; b++){ int t = bsum[b]; bbase[b] = run; run += t; }
    offs[NNODES] = NEDGES;
  }
}

// finalize offs; init per-chunk staging cursors
__global__ void k_scan3(int* __restrict__ offs, const int* __restrict__ bbase, int* __restrict__ ccur){
  int n = blockIdx.x*256 + threadIdx.x;
  if (n < NNODES){
    int o = offs[n] + bbase[n >> 10];
    offs[n] = o;
    if ((n & (CHUNK-1)) == 0) ccur[n / CHUNK] = o;
  }
}

// ---------------- pass 1: bin edges by 512-node chunk (coalesced staging writes) ----------------
// staged record: .x = (src&511)<<17 | tgt ; .y = idx<<16 | half(frac)
__global__ void k_bin(const int* __restrict__ src, const int* __restrict__ tgt,
                      const float* __restrict__ elen, int* ccur,
                      int2* __restrict__ eb){
  __shared__ int lcnt[NCHUNK];
  __shared__ int lbase[NCHUNK];
  __shared__ int loff[NCHUNK];
  int t = threadIdx.x;
  int e0 = blockIdx.x * 2048;
  if (t < NCHUNK){ lcnt[t] = 0; loff[t] = 0; }
  __syncthreads();
  #pragma unroll
  for (int k = 0; k < 8; k++){
    int e = e0 + k*256 + t;
    if (e < NEDGES) atomicAdd(&lcnt[src[e] / CHUNK], 1);
  }
  __syncthreads();
  if (t < NCHUNK && lcnt[t] > 0) lbase[t] = atomicAdd(&ccur[t], lcnt[t]);
  __syncthreads();
  #pragma unroll
  for (int k = 0; k < 8; k++){
    int e = e0 + k*256 + t;
    if (e < NEDGES){
      int s = src[e];
      int c = s / CHUNK;
      int r = atomicAdd(&loff[c], 1);
      float key = (elen[e] - R_MIN_) * ((float)(TBL-1)/(R_MAX_-R_MIN_));
      key = fminf(fmaxf(key, 0.f), (float)(TBL-1) - 1e-3f);
      int idx = (int)key;
      float fr = key - (float)idx;
      unsigned short fh = __half_as_ushort(__float2half_rn(fr));
      eb[lbase[c] + r] = make_int2(((s & (CHUNK-1)) << 17) | tgt[e],
                                   (idx << 16) | (int)fh);
    }
  }
}

// ---------------- pass 2: fine scatter within an L2-resident chunk region ----------------
__global__ void k_fine(const int* __restrict__ offs, const int2* __restrict__ eb,
                       int2* __restrict__ ep){
  __shared__ int lcur[CHUNK];
  int c = blockIdx.x;
  int t = threadIdx.x;                    // 512 threads
  int n0 = c * CHUNK;
  int n1 = min(n0 + CHUNK, NNODES);
  int cnt = n1 - n0;
  if (t < cnt) lcur[t] = offs[n0 + t];
  __syncthreads();
  int j0 = offs[n0], j1 = offs[n1];
  for (int e = j0 + t; e < j1; e += 512){
    int2 rec = eb[e];
    int sl = ((unsigned)rec.x) >> 17;
    int tg = rec.x & 0x1FFFF;
    int pos = atomicAdd(&lcur[sl], 1);
    ep[pos] = make_int2(tg, rec.y);
  }
}

// ---------------- Gaussian table, interleaved fp16 form ----------------
// Gt2h row r, channel c: halves [4c]=g0f, [4c+1]=g0s, [4c+2]=g1f(row r+1), [4c+3]=g1s
__global__ void k_gauss(const float* __restrict__ Wf, const float* __restrict__ bf,
                        const float* __restrict__ Ws, const float* __restrict__ bs,
                        __half* __restrict__ Gt2h){
  __shared__ float attr[64];
  int bi = blockIdx.x;
  int i = bi / TBL, r = bi % TBL;
  int t = threadIdx.x;
  float d = R_MIN_ + (R_MAX_-R_MIN_) * (float)r / (float)(TBL-1);
  if (t < 64){
    float cj = 1.f + 5.f * (float)t / 63.f;
    float u = (d - cj) * (64.f/5.f);
    attr[t] = __expf(-0.5f*u*u);
  }
  __syncthreads();
  int c = t >> 1;
  int side = t & 1;
  const float* W = (side ? Ws : Wf) + i*192*64 + 128*64 + c;
  float acc = (side ? bs : bf)[i*64 + c];
  #pragma unroll 8
  for (int j = 0; j < 64; j++) acc = fmaf(attr[j], W[j*64], acc);
  __half h = __float2half_rn(acc);
  __half* base = Gt2h + (size_t)i*TBL*256;
  base[(size_t)r*256 + 4*c + side] = h;
  if (r > 0) base[(size_t)(r-1)*256 + 4*c + 2 + side] = h;
}

// ---------------- Wcat pack ----------------
__global__ void k_wcat(const float* __restrict__ Wf, const float* __restrict__ Ws,
                       float* __restrict__ Wcat){
  int idx = blockIdx.x*256 + threadIdx.x;
  if (idx >= 3*64*256) return;
  int i = idx / (64*256);
  int rem = idx % (64*256);
  int k = rem / 256, c = rem % 256;
  float v;
  if (c < 128){
    int p = c >> 1; bool ss = (c & 1);
    v = (ss ? Ws : Wf)[i*192*64 + k*64 + p];
  } else {
    int p = (c-128) >> 1; bool ss = (c & 1);
    v = (ss ? Ws : Wf)[i*192*64 + (64+k)*64 + p];
  }
  Wcat[i*64*256 + k*256 + c] = v;
}

// ---------------- node transform: 32 nodes x 256 cols; p and q stored fp16 ----------------
__global__ void k_ntrans(const float* __restrict__ x, const float* __restrict__ Wc,
                         __half2* __restrict__ pqh){
  __shared__ float xs[32*64];       // 8 KB
  int n0 = blockIdx.x * 32;         // 3125 blocks exact
  int t = threadIdx.x;              // 256
  ((float4*)xs)[t]       = ((const float4*)(x + (size_t)n0*64))[t];
  ((float4*)xs)[t + 256] = ((const float4*)(x + (size_t)n0*64))[t + 256];
  __syncthreads();
  int cg = t & 63, ng = t >> 6;     // 64 col-groups x 4 cols; 4 node-groups x 8 nodes
  float4 acc[8];
  #pragma unroll
  for (int i = 0; i < 8; i++) acc[i] = make_float4(0.f,0.f,0.f,0.f);
  const float* wp = Wc + 4*cg;
  const float* xp = xs + ng*8*64;
  #pragma unroll 2
  for (int k = 0; k < 64; k += 4){
    float4 w0 = *(const float4*)(wp + (k+0)*256);
    float4 w1 = *(const float4*)(wp + (k+1)*256);
    float4 w2 = *(const float4*)(wp + (k+2)*256);
    float4 w3 = *(const float4*)(wp + (k+3)*256);
    #pragma unroll
    for (int nn = 0; nn < 8; nn++){
      float4 xv = *(const float4*)(xp + nn*64 + k);
      fma4(acc[nn], xv.x, w0); fma4(acc[nn], xv.y, w1);
      fma4(acc[nn], xv.z, w2); fma4(acc[nn], xv.w, w3);
    }
  }
  #pragma unroll
  for (int nn = 0; nn < 8; nn++){
    int node = n0 + ng*8 + nn;
    __half2 h0 = __float22half2_rn(make_float2(acc[nn].x, acc[nn].y));
    __half2 h1 = __float22half2_rn(make_float2(acc[nn].z, acc[nn].w));
    __half2* dst = pqh + (size_t)node*128 + 2*cg;
    dst[0] = h0; dst[1] = h1;
  }
}

// ---------------- edge pass: wave per node, metadata-pipelined, fp16 tables ----------------
__global__ void k_edge(const __half2* __restrict__ pqh,
                       const int* __restrict__ offs, const int2* __restrict__ ep,
                       const __half* __restrict__ Gt2h, const float* __restrict__ lng,
                       const float* __restrict__ lnb, float* __restrict__ x){
  int wid  = (blockIdx.x*256 + threadIdx.x) >> 6;
  int lane = threadIdx.x & 63;
  int n = wid;
  int j0 = __builtin_amdgcn_readfirstlane(offs[n]);
  int j1 = __builtin_amdgcn_readfirstlane(offs[n+1]);
  int nfull = (j1 - j0) >> 3;
  int2 eb8[8];
  if (nfull > 0){
    #pragma unroll
    for (int i = 0; i < 8; i++) eb8[i] = ep[j0 + i];
  }
  float2 pp = __half22float2(pqh[(size_t)n*128 + lane]);
  v2f pv; pv.x = pp.x; pv.y = pp.y;
  float acc = 0.f;
  int u = j0;
  for (int b = 0; b < nfull; b++){
    int tgv[8], idxv[8]; float frv[8];
    #pragma unroll
    for (int i = 0; i < 8; i++){
      tgv[i]  = eb8[i].x;
      idxv[i] = ((unsigned)eb8[i].y) >> 16;
      frv[i]  = __half2float(__ushort_as_half((unsigned short)(eb8[i].y & 0xffff)));
    }
    __half2 qr[8]; __half2 ga[8]; __half2 gb[8];
    #pragma unroll
    for (int i = 0; i < 8; i++){
      qr[i] = pqh[(size_t)tgv[i]*128 + 64 + lane];
      const __half2* gp = (const __half2*)(Gt2h + (size_t)idxv[i]*256 + 4*lane);
      ga[i] = gp[0];
      gb[i] = gp[1];
    }
    if (b + 1 < nfull){
      #pragma unroll
      for (int i = 0; i < 8; i++) eb8[i] = ep[u + 8 + i];
    }
    #pragma unroll
    for (int i = 0; i < 8; i++){
      float2 qf = __half22float2(qr[i]);
      float2 g0f = __half22float2(ga[i]);
      float2 g1f = __half22float2(gb[i]);
      v2f qv; qv.x = qf.x; qv.y = qf.y;
      v2f g0; g0.x = g0f.x; g0.y = g0f.y;
      v2f g1; g1.x = g1f.x; g1.y = g1f.y;
      v2f fr2; fr2.x = frv[i]; fr2.y = frv[i];
      v2f z = pv + qv + g0 + fr2*(g1 - g0);
      acc = fmaf(sigmoid_f(z.x), softplus_f(z.y), acc);
    }
    u += 8;
  }
  for (; u < j1; u++){
    int2 e = ep[u];
    int tg = e.x;
    int idx = ((unsigned)e.y) >> 16;
    float fr0 = __half2float(__ushort_as_half((unsigned short)(e.y & 0xffff)));
    float2 qf = __half22float2(pqh[(size_t)tg*128 + 64 + lane]);
    const __half2* gp = (const __half2*)(Gt2h + (size_t)idx*256 + 4*lane);
    float2 g0f = __half22float2(gp[0]);
    float2 g1f = __half22float2(gp[1]);
    float rf = fmaf(fr0, g1f.x - g0f.x, g0f.x);
    float rs = fmaf(fr0, g1f.y - g0f.y, g0f.y);
    acc = fmaf(sigmoid_f(pp.x + qf.x + rf), softplus_f(pp.y + qf.y + rs), acc);
  }
  float s1 = acc, s2 = acc*acc;
  #pragma unroll
  for (int o = 32; o > 0; o >>= 1){ s1 += __shfl_xor(s1, o, 64); s2 += __shfl_xor(s2, o, 64); }
  float mu  = s1 * (1.f/64.f);
  float var = s2 * (1.f/64.f) - mu*mu;
  float inv = rsqrtf(fmaxf(var, 0.f) + 1e-5f);
  float y = (acc - mu) * inv * lng[lane] + lnb[lane];
  x[(size_t)n*64 + lane] += y;
}

// ---------------- fused head with K=8 register-prefetched weights ----------------
__global__ void k_head(const float* __restrict__ x,
                       const float* __restrict__ W1, const float* __restrict__ b1,
                       const float* __restrict__ g1, const float* __restrict__ bt1,
                       const float* __restrict__ W2, const float* __restrict__ b2,
                       const float* __restrict__ g2, const float* __restrict__ bt2,
                       const float* __restrict__ Wout, const int* __restrict__ batch,
                       float* gsum, int* gcnt){
  __shared__ float xs[32*64];       // 8 KB
  __shared__ float hs[32*128];      // 16 KB
  __shared__ float es[32];
  int n0 = blockIdx.x * 32;         // 3125 blocks
  int t = threadIdx.x;              // 256
  ((float4*)xs)[t]       = ((const float4*)(x + (size_t)n0*64))[t];
  ((float4*)xs)[t + 256] = ((const float4*)(x + (size_t)n0*64))[t + 256];
  __syncthreads();
  int cg = t & 31, ng = t >> 5;     // 32 col-groups x 4 cols; 8 node-groups x 4 nodes

  // ---- layer 1: 64 -> 128, LN, softplus, into hs ----
  {
    float4 acc[4];
    #pragma unroll
    for (int i = 0; i < 4; i++) acc[i] = make_float4(0.f,0.f,0.f,0.f);
    const float* wp = W1 + 4*cg;
    const float* xp = xs + ng*4*64;
    float4 w[8];
    #pragma unroll
    for (int j = 0; j < 8; j++) w[j] = *(const float4*)(wp + j*128);
    for (int k = 0; k < 64; k += 8){
      float4 wn[8];
      int kn = (k + 8 < 64) ? k + 8 : 0;
      #pragma unroll
      for (int j = 0; j < 8; j++) wn[j] = *(const float4*)(wp + (kn+j)*128);
      #pragma unroll
      for (int h = 0; h < 2; h++){
        #pragma unroll
        for (int nn = 0; nn < 4; nn++){
          float4 xv = *(const float4*)(xp + nn*64 + k + h*4);
          fma4(acc[nn], xv.x, w[h*4+0]); fma4(acc[nn], xv.y, w[h*4+1]);
          fma4(acc[nn], xv.z, w[h*4+2]); fma4(acc[nn], xv.w, w[h*4+3]);
        }
      }
      #pragma unroll
      for (int j = 0; j < 8; j++) w[j] = wn[j];
    }
    float4 bv  = *(const float4*)(b1  + 4*cg);
    float4 gv  = *(const float4*)(g1  + 4*cg);
    float4 btv = *(const float4*)(bt1 + 4*cg);
    #pragma unroll
    for (int nn = 0; nn < 4; nn++){
      float4 v = acc[nn];
      v.x += bv.x; v.y += bv.y; v.z += bv.z; v.w += bv.w;
      float s1 = v.x + v.y + v.z + v.w;
      float s2 = v.x*v.x + v.y*v.y + v.z*v.z + v.w*v.w;
      #pragma unroll
      for (int o = 16; o > 0; o >>= 1){ s1 += __shfl_xor(s1, o, 64); s2 += __shfl_xor(s2, o, 64); }
      float mu  = s1 * (1.f/128.f);
      float var = s2 * (1.f/128.f) - mu*mu;
      float inv = rsqrtf(fmaxf(var, 0.f) + 1e-5f);
      float4 o4;
      o4.x = softplus_f((v.x - mu)*inv*gv.x + btv.x);
      o4.y = softplus_f((v.y - mu)*inv*gv.y + btv.y);
      o4.z = softplus_f((v.z - mu)*inv*gv.z + btv.z);
      o4.w = softplus_f((v.w - mu)*inv*gv.w + btv.w);
      *(float4*)(hs + (ng*4 + nn)*128 + 4*cg) = o4;
    }
  }
  __syncthreads();

  // ---- layer 2: 128 -> 128, LN, softplus, proj -> per-node energy in es ----
  {
    float4 acc[4];
    #pragma unroll
    for (int i = 0; i < 4; i++) acc[i] = make_float4(0.f,0.f,0.f,0.f);
    const float* wp = W2 + 4*cg;
    const float* hp = hs + ng*4*128;
    float4 w[8];
    #pragma unroll
    for (int j = 0; j < 8; j++) w[j] = *(const float4*)(wp + j*128);
    for (int k = 0; k < 128; k += 8){
      float4 wn[8];
      int kn = (k + 8 < 128) ? k + 8 : 0;
      #pragma unroll
      for (int j = 0; j < 8; j++) wn[j] = *(const float4*)(wp + (kn+j)*128);
      #pragma unroll
      for (int h = 0; h < 2; h++){
        #pragma unroll
        for (int nn = 0; nn < 4; nn++){
          float4 hv = *(const float4*)(hp + nn*128 + k + h*4);
          fma4(acc[nn], hv.x, w[h*4+0]); fma4(acc[nn], hv.y, w[h*4+1]);
          fma4(acc[nn], hv.z, w[h*4+2]); fma4(acc[nn], hv.w, w[h*4+3]);
        }
      }
      #pragma unroll
      for (int j = 0; j < 8; j++) w[j] = wn[j];
    }
    float4 bv  = *(const float4*)(b2  + 4*cg);
    float4 gv  = *(const float4*)(g2  + 4*cg);
    float4 btv = *(const float4*)(bt2 + 4*cg);
    float4 wo  = *(const float4*)(Wout + 4*cg);
    #pragma unroll
    for (int nn = 0; nn < 4; nn++){
      float4 v = acc[nn];
      v.x += bv.x; v.y += bv.y; v.z += bv.z; v.w += bv.w;
      float s1 = v.x + v.y + v.z + v.w;
      float s2 = v.x*v.x + v.y*v.y + v.z*v.z + v.w*v.w;
      #pragma unroll
      for (int o = 16; o > 0; o >>= 1){ s1 += __shfl_xor(s1, o, 64); s2 += __shfl_xor(s2, o, 64); }
      float mu  = s1 * (1.f/128.f);
      float var = s2 * (1.f/128.f) - mu*mu;
      float inv = rsqrtf(fmaxf(var, 0.f) + 1e-5f);
      float ev = softplus_f((v.x - mu)*inv*gv.x + btv.x) * wo.x
               + softplus_f((v.y - mu)*inv*gv.y + btv.y) * wo.y
               + softplus_f((v.z - mu)*inv*gv.z + btv.z) * wo.z
               + softplus_f((v.w - mu)*inv*gv.w + btv.w) * wo.w;
      #pragma unroll
      for (int o = 16; o > 0; o >>= 1) ev += __shfl_xor(ev, o, 64);
      if (cg == 0) es[ng*4 + nn] = ev;
    }
  }
  __syncthreads();

  // ---- segmented reduction over the sorted 32-node tile ----
  if (t < 32){
    int node = n0 + t;
    int g = batch[node];
    bool head = (t == 0) || (batch[node-1] != g);
    if (head){
      float s = 0.f; int c = 0;
      int j = t;
      while (j < 32 && batch[n0+j] == g){ s += es[j]; c++; j++; }
      atomicAdd(&gsum[g], s);
      atomicAdd(&gcnt[g], c);
    }
  }
}

// ---------------- final ----------------
__global__ void k_final(const float* __restrict__ gsum, const int* __restrict__ gcnt,
                        const float* __restrict__ bout, float* __restrict__ out){
  int g = threadIdx.x;
  if (g < NGRAPH)
    out[g] = gsum[g] / fmaxf((float)gcnt[g], 1.f) + bout[0];
}

extern "C" void kernel_launch(void* const* d_in, const int* in_sizes, int n_in,
                              void* d_out, int out_size, void* d_ws, size_t ws_size,
                              hipStream_t stream){
  const int*   numbers = (const int*)d_in[0];
  const int*   eidx    = (const int*)d_in[1];
  const float* elen    = (const float*)d_in[2];
  const int*   batch   = (const int*)d_in[3];
  const float* embed   = (const float*)d_in[4];
  const float* Wf      = (const float*)d_in[5];
  const float* bf      = (const float*)d_in[6];
  const float* Ws      = (const float*)d_in[7];
  const float* bs      = (const float*)d_in[8];
  const float* lng     = (const float*)d_in[9];
  const float* lnb     = (const float*)d_in[10];
  const float* W1      = (const float*)d_in[11];
  const float* b1      = (const float*)d_in[12];
  const float* g1      = (const float*)d_in[13];
  const float* bt1     = (const float*)d_in[14];
  const float* W2      = (const float*)d_in[15];
  const float* b2      = (const float*)d_in[16];
  const float* g2      = (const float*)d_in[17];
  const float* bt2     = (const float*)d_in[18];
  const float* Wout    = (const float*)d_in[19];
  const float* bout    = (const float*)d_in[20];
  const int* src = eidx;
  const int* tgt = eidx + NEDGES;

  float*   x    = (float*)d_ws;                          // N*64 f32
  __half2* pqh  = (__half2*)(x + (size_t)NNODES*64);     // N*128 half2
  __half*  Gt2h = (__half*)(pqh + (size_t)NNODES*128);   // 3*TBL*256 half
  float*   Wcat = (float*)(Gt2h + (size_t)3*TBL*256);    // 3*64*256 f32
  int2*    ep   = (int2*)(Wcat + (size_t)3*64*256);      // E int2 (final CSR)
  int2*    ebuf = ep + NEDGES;                           // E int2 (staging)
  int*     offs = (int*)(ebuf + NEDGES);                 // N+1
  int*     deg  = offs + NNODES + 1;                     // N
  int*     ccur = deg + NNODES;                          // NCHUNK (pad 256)
  int*     bsum = ccur + 256;                            // 128
  int*     bbase= bsum + 128;                            // 128
  float*   gsum = (float*)(bbase + 128);                 // 256
  int*     gcnt = (int*)(gsum + NGRAPH);                 // 256
  float*   out  = (float*)d_out;

  k_init  <<<(NNODES+255)/256, 256, 0, stream>>>(deg, gsum, gcnt);
  k_embed <<<(NNODES*64+255)/256, 256, 0, stream>>>(numbers, embed, x);

  k_hist  <<<(NEDGES+255)/256, 256, 0, stream>>>(src, deg);
  k_scan1 <<<NB1, 1024, 0, stream>>>(deg, offs, bsum);
  k_scan2 <<<1, 64, 0, stream>>>(bsum, bbase, offs);
  k_scan3 <<<(NNODES+255)/256, 256, 0, stream>>>(offs, bbase, ccur);
  k_bin   <<<(NEDGES+2047)/2048, 256, 0, stream>>>(src, tgt, elen, ccur, ebuf);
  k_fine  <<<NCHUNK, 512, 0, stream>>>(offs, ebuf, ep);

  k_gauss <<<3*TBL, 128, 0, stream>>>(Wf, bf, Ws, bs, Gt2h);
  k_wcat  <<<(3*64*256+255)/256, 256, 0, stream>>>(Wf, Ws, Wcat);

  for (int i = 0; i < NCONV; i++){
    k_ntrans<<<NNODES/32, 256, 0, stream>>>(x, Wcat + (size_t)i*64*256, pqh);
    k_edge  <<<NNODES/4, 256, 0, stream>>>(pqh, offs, ep,
                                           Gt2h + (size_t)i*TBL*256,
                                           lng + i*64, lnb + i*64, x);
  }

  k_head<<<NNODES/32, 256, 0, stream>>>(x, W1, b1, g1, bt1,
                                        W2, b2, g2, bt2, Wout, batch, gsum, gcnt);
  k_final<<<1, 256, 0, stream>>>(gsum, gcnt, bout, out);
}

// Round 12
// 806.854 us; speedup vs baseline: 1.1665x; 1.0782x over previous
//
#include <hip/hip_runtime.h>
#include <hip/hip_fp16.h>
#include <math.h>

#define NNODES 100000
#define NEDGES 1600000
#define NGRAPH 256
#define NCONV  3
#define TBL    4096
#define CHUNK  512
#define NCHUNK 196         // ceil(100000/512)
#define R_MIN_ 1.0f
#define R_MAX_ 6.0f

typedef float v2f __attribute__((ext_vector_type(2)));

__device__ __forceinline__ float softplus_f(float x){
  return fmaxf(x, 0.f) + __logf(1.f + __expf(-fabsf(x)));
}
__device__ __forceinline__ float sigmoid_f(float x){
  return __builtin_amdgcn_rcpf(1.f + __expf(-x));
}
__device__ __forceinline__ void fma4(float4& a, float s, const float4 w){
  a.x = fmaf(s, w.x, a.x); a.y = fmaf(s, w.y, a.y);
  a.z = fmaf(s, w.z, a.z); a.w = fmaf(s, w.w, a.w);
}

// ---------------- init: zero chunk counters + graph accumulators ----------------
__global__ void k_init(int* ccnt, float* gsum, int* gcnt){
  int i = blockIdx.x*256 + threadIdx.x;
  if (i < 256) ccnt[i] = 0;
  if (i < NGRAPH){ gsum[i] = 0.f; gcnt[i] = 0; }
}

// ---------------- embedding gather ----------------
__global__ void k_embed(const int* __restrict__ numbers, const float* __restrict__ embed,
                        float* __restrict__ x){
  int i = blockIdx.x*256 + threadIdx.x;
  if (i >= NNODES*64) return;
  int n = i >> 6, c = i & 63;
  x[i] = embed[numbers[n]*64 + c];
}

// ---------------- chunk count: LDS histogram then 196 global atomics per block ----------------
__global__ void k_cnt(const int* __restrict__ src, int* ccnt){
  __shared__ int l[NCHUNK];
  int t = threadIdx.x;
  int e0 = blockIdx.x * 2048;
  if (t < NCHUNK) l[t] = 0;
  __syncthreads();
  #pragma unroll
  for (int k = 0; k < 8; k++){
    int e = e0 + k*256 + t;
    if (e < NEDGES) atomicAdd(&l[src[e] / CHUNK], 1);
  }
  __syncthreads();
  if (t < NCHUNK && l[t] > 0) atomicAdd(&ccnt[t], l[t]);
}

// ---------------- chunk scan: cbase prefix, init ccur, sentinel ----------------
__global__ void k_cscan(const int* __restrict__ ccnt, int* __restrict__ cbase,
                        int* __restrict__ ccur, int* __restrict__ offs){
  int t = threadIdx.x;
  if (t == 0){
    int run = 0;
    for (int c = 0; c < NCHUNK; c++){ cbase[c] = run; run += ccnt[c]; }
    cbase[NCHUNK] = NEDGES;
    offs[NNODES] = NEDGES;
  }
  __syncthreads();
  if (t < NCHUNK) ccur[t] = cbase[t];
}

// ---------------- pass 1: bin edges by 512-node chunk ----------------
// staged record: .x = (src&511)<<17 | tgt ; .y = nearest-neighbor table idx
__global__ void k_bin(const int* __restrict__ src, const int* __restrict__ tgt,
                      const float* __restrict__ elen, int* ccur,
                      int2* __restrict__ eb){
  __shared__ int lcnt[NCHUNK];
  __shared__ int lbase[NCHUNK];
  __shared__ int loff[NCHUNK];
  int t = threadIdx.x;
  int e0 = blockIdx.x * 2048;
  if (t < NCHUNK){ lcnt[t] = 0; loff[t] = 0; }
  __syncthreads();
  #pragma unroll
  for (int k = 0; k < 8; k++){
    int e = e0 + k*256 + t;
    if (e < NEDGES) atomicAdd(&lcnt[src[e] / CHUNK], 1);
  }
  __syncthreads();
  if (t < NCHUNK && lcnt[t] > 0) lbase[t] = atomicAdd(&ccur[t], lcnt[t]);
  __syncthreads();
  #pragma unroll
  for (int k = 0; k < 8; k++){
    int e = e0 + k*256 + t;
    if (e < NEDGES){
      int s = src[e];
      int c = s / CHUNK;
      int r = atomicAdd(&loff[c], 1);
      float key = (elen[e] - R_MIN_) * ((float)(TBL-1)/(R_MAX_-R_MIN_));
      key = fmaxf(key, 0.f);
      int idx = (int)(key + 0.5f);
      if (idx > TBL-1) idx = TBL-1;
      eb[lbase[c] + r] = make_int2(((s & (CHUNK-1)) << 17) | tgt[e], idx);
    }
  }
}

// ---------------- pass 2: fine scatter; also builds offs via LDS count+scan ----------------
__global__ void k_fine(const int* __restrict__ cbase, const int2* __restrict__ eb,
                       int2* __restrict__ ep, int* __restrict__ offs){
  __shared__ int lcnt[CHUNK];
  __shared__ int lsc[CHUNK];
  int c = blockIdx.x;
  int t = threadIdx.x;                    // 512 threads
  int n0 = c * CHUNK;
  int n1 = min(n0 + CHUNK, NNODES);
  int cnt = n1 - n0;
  int j0 = cbase[c], j1 = cbase[c+1];
  lcnt[t] = 0;
  __syncthreads();
  for (int e = j0 + t; e < j1; e += 512)
    atomicAdd(&lcnt[((unsigned)eb[e].x) >> 17], 1);
  __syncthreads();
  lsc[t] = lcnt[t];
  __syncthreads();
  for (int d = 1; d < 512; d <<= 1){
    int v = (t >= d) ? lsc[t-d] : 0;
    __syncthreads();
    lsc[t] += v;
    __syncthreads();
  }
  int excl = lsc[t] - lcnt[t];
  if (t < cnt) offs[n0 + t] = j0 + excl;
  __syncthreads();
  lcnt[t] = j0 + excl;                    // reuse as cursors
  __syncthreads();
  for (int e = j0 + t; e < j1; e += 512){
    int2 rec = eb[e];
    int sl = ((unsigned)rec.x) >> 17;
    int pos = atomicAdd(&lcnt[sl], 1);
    ep[pos] = make_int2(rec.x & 0x1FFFF, rec.y);
  }
}

// ---------------- Gaussian table, fp16, nearest-neighbor (no lerp pair) ----------------
// Gth row r: 128 halves, [2c]=f-side, [2c+1]=s-side
__global__ void k_gauss(const float* __restrict__ Wf, const float* __restrict__ bf,
                        const float* __restrict__ Ws, const float* __restrict__ bs,
                        __half* __restrict__ Gth){
  __shared__ float attr[64];
  int bi = blockIdx.x;                  // 3*TBL
  int i = bi / TBL, r = bi % TBL;
  int t = threadIdx.x;                  // 128
  float d = R_MIN_ + (R_MAX_-R_MIN_) * (float)r / (float)(TBL-1);
  if (t < 64){
    float cj = 1.f + 5.f * (float)t / 63.f;
    float u = (d - cj) * (64.f/5.f);
    attr[t] = __expf(-0.5f*u*u);
  }
  __syncthreads();
  int c = t >> 1;
  int side = t & 1;
  const float* W = (side ? Ws : Wf) + i*192*64 + 128*64 + c;
  float acc = (side ? bs : bf)[i*64 + c];
  #pragma unroll 8
  for (int j = 0; j < 64; j++) acc = fmaf(attr[j], W[j*64], acc);
  Gth[((size_t)i*TBL + r)*128 + t] = __float2half_rn(acc);
}

// ---------------- Wcat pack ----------------
__global__ void k_wcat(const float* __restrict__ Wf, const float* __restrict__ Ws,
                       float* __restrict__ Wcat){
  int idx = blockIdx.x*256 + threadIdx.x;
  if (idx >= 3*64*256) return;
  int i = idx / (64*256);
  int rem = idx % (64*256);
  int k = rem / 256, c = rem % 256;
  float v;
  if (c < 128){
    int p = c >> 1; bool ss = (c & 1);
    v = (ss ? Ws : Wf)[i*192*64 + k*64 + p];
  } else {
    int p = (c-128) >> 1; bool ss = (c & 1);
    v = (ss ? Ws : Wf)[i*192*64 + (64+k)*64 + p];
  }
  Wcat[i*64*256 + k*256 + c] = v;
}

// ---------------- node transform: 32 nodes x 256 cols; p and q stored fp16 ----------------
__global__ void k_ntrans(const float* __restrict__ x, const float* __restrict__ Wc,
                         __half2* __restrict__ pqh){
  __shared__ float xs[32*64];       // 8 KB
  int n0 = blockIdx.x * 32;         // 3125 blocks exact
  int t = threadIdx.x;              // 256
  ((float4*)xs)[t]       = ((const float4*)(x + (size_t)n0*64))[t];
  ((float4*)xs)[t + 256] = ((const float4*)(x + (size_t)n0*64))[t + 256];
  __syncthreads();
  int cg = t & 63, ng = t >> 6;     // 64 col-groups x 4 cols; 4 node-groups x 8 nodes
  float4 acc[8];
  #pragma unroll
  for (int i = 0; i < 8; i++) acc[i] = make_float4(0.f,0.f,0.f,0.f);
  const float* wp = Wc + 4*cg;
  const float* xp = xs + ng*8*64;
  #pragma unroll 2
  for (int k = 0; k < 64; k += 4){
    float4 w0 = *(const float4*)(wp + (k+0)*256);
    float4 w1 = *(const float4*)(wp + (k+1)*256);
    float4 w2 = *(const float4*)(wp + (k+2)*256);
    float4 w3 = *(const float4*)(wp + (k+3)*256);
    #pragma unroll
    for (int nn = 0; nn < 8; nn++){
      float4 xv = *(const float4*)(xp + nn*64 + k);
      fma4(acc[nn], xv.x, w0); fma4(acc[nn], xv.y, w1);
      fma4(acc[nn], xv.z, w2); fma4(acc[nn], xv.w, w3);
    }
  }
  #pragma unroll
  for (int nn = 0; nn < 8; nn++){
    int node = n0 + ng*8 + nn;
    __half2 h0 = __float22half2_rn(make_float2(acc[nn].x, acc[nn].y));
    __half2 h1 = __float22half2_rn(make_float2(acc[nn].z, acc[nn].w));
    __half2* dst = pqh + (size_t)node*128 + 2*cg;
    dst[0] = h0; dst[1] = h1;
  }
}

// ---------------- edge pass: wave per node, NN table, 2 loads/edge ----------------
__global__ void k_edge(const __half2* __restrict__ pqh,
                       const int* __restrict__ offs, const int2* __restrict__ ep,
                       const __half* __restrict__ Gth, const float* __restrict__ lng,
                       const float* __restrict__ lnb, float* __restrict__ x){
  int wid  = (blockIdx.x*256 + threadIdx.x) >> 6;
  int lane = threadIdx.x & 63;
  int n = wid;
  int j0 = __builtin_amdgcn_readfirstlane(offs[n]);
  int j1 = __builtin_amdgcn_readfirstlane(offs[n+1]);
  int nfull = (j1 - j0) >> 3;
  int2 eb8[8];
  if (nfull > 0){
    #pragma unroll
    for (int i = 0; i < 8; i++) eb8[i] = ep[j0 + i];
  }
  float2 pp = __half22float2(pqh[(size_t)n*128 + lane]);
  float acc = 0.f;
  int u = j0;
  for (int b = 0; b < nfull; b++){
    int tgv[8], idxv[8];
    #pragma unroll
    for (int i = 0; i < 8; i++){ tgv[i] = eb8[i].x; idxv[i] = eb8[i].y; }
    __half2 qr[8], gr[8];
    #pragma unroll
    for (int i = 0; i < 8; i++){
      qr[i] = pqh[(size_t)tgv[i]*128 + 64 + lane];
      gr[i] = *(const __half2*)(Gth + (size_t)idxv[i]*128 + 2*lane);
    }
    if (b + 1 < nfull){
      #pragma unroll
      for (int i = 0; i < 8; i++) eb8[i] = ep[u + 8 + i];
    }
    #pragma unroll
    for (int i = 0; i < 8; i++){
      float2 qf = __half22float2(qr[i]);
      float2 gf = __half22float2(gr[i]);
      float zf = pp.x + qf.x + gf.x;
      float zs = pp.y + qf.y + gf.y;
      acc = fmaf(sigmoid_f(zf), softplus_f(zs), acc);
    }
    u += 8;
  }
  for (; u < j1; u++){
    int2 e = ep[u];
    float2 qf = __half22float2(pqh[(size_t)e.x*128 + 64 + lane]);
    float2 gf = __half22float2(*(const __half2*)(Gth + (size_t)e.y*128 + 2*lane));
    acc = fmaf(sigmoid_f(pp.x + qf.x + gf.x), softplus_f(pp.y + qf.y + gf.y), acc);
  }
  float s1 = acc, s2 = acc*acc;
  #pragma unroll
  for (int o = 32; o > 0; o >>= 1){ s1 += __shfl_xor(s1, o, 64); s2 += __shfl_xor(s2, o, 64); }
  float mu  = s1 * (1.f/64.f);
  float var = s2 * (1.f/64.f) - mu*mu;
  float inv = rsqrtf(fmaxf(var, 0.f) + 1e-5f);
  float y = (acc - mu) * inv * lng[lane] + lnb[lane];
  x[(size_t)n*64 + lane] += y;
}

// ---------------- fused head with K=8 register-prefetched weights ----------------
__global__ void k_head(const float* __restrict__ x,
                       const float* __restrict__ W1, const float* __restrict__ b1,
                       const float* __restrict__ g1, const float* __restrict__ bt1,
                       const float* __restrict__ W2, const float* __restrict__ b2,
                       const float* __restrict__ g2, const float* __restrict__ bt2,
                       const float* __restrict__ Wout, const int* __restrict__ batch,
                       float* gsum, int* gcnt){
  __shared__ float xs[32*64];       // 8 KB
  __shared__ float hs[32*128];      // 16 KB
  __shared__ float es[32];
  int n0 = blockIdx.x * 32;         // 3125 blocks
  int t = threadIdx.x;              // 256
  ((float4*)xs)[t]       = ((const float4*)(x + (size_t)n0*64))[t];
  ((float4*)xs)[t + 256] = ((const float4*)(x + (size_t)n0*64))[t + 256];
  __syncthreads();
  int cg = t & 31, ng = t >> 5;     // 32 col-groups x 4 cols; 8 node-groups x 4 nodes

  // ---- layer 1: 64 -> 128, LN, softplus, into hs ----
  {
    float4 acc[4];
    #pragma unroll
    for (int i = 0; i < 4; i++) acc[i] = make_float4(0.f,0.f,0.f,0.f);
    const float* wp = W1 + 4*cg;
    const float* xp = xs + ng*4*64;
    float4 w[8];
    #pragma unroll
    for (int j = 0; j < 8; j++) w[j] = *(const float4*)(wp + j*128);
    for (int k = 0; k < 64; k += 8){
      float4 wn[8];
      int kn = (k + 8 < 64) ? k + 8 : 0;
      #pragma unroll
      for (int j = 0; j < 8; j++) wn[j] = *(const float4*)(wp + (kn+j)*128);
      #pragma unroll
      for (int h = 0; h < 2; h++){
        #pragma unroll
        for (int nn = 0; nn < 4; nn++){
          float4 xv = *(const float4*)(xp + nn*64 + k + h*4);
          fma4(acc[nn], xv.x, w[h*4+0]); fma4(acc[nn], xv.y, w[h*4+1]);
          fma4(acc[nn], xv.z, w[h*4+2]); fma4(acc[nn], xv.w, w[h*4+3]);
        }
      }
      #pragma unroll
      for (int j = 0; j < 8; j++) w[j] = wn[j];
    }
    float4 bv  = *(const float4*)(b1  + 4*cg);
    float4 gv  = *(const float4*)(g1  + 4*cg);
    float4 btv = *(const float4*)(bt1 + 4*cg);
    #pragma unroll
    for (int nn = 0; nn < 4; nn++){
      float4 v = acc[nn];
      v.x += bv.x; v.y += bv.y; v.z += bv.z; v.w += bv.w;
      float s1 = v.x + v.y + v.z + v.w;
      float s2 = v.x*v.x + v.y*v.y + v.z*v.z + v.w*v.w;
      #pragma unroll
      for (int o = 16; o > 0; o >>= 1){ s1 += __shfl_xor(s1, o, 64); s2 += __shfl_xor(s2, o, 64); }
      float mu  = s1 * (1.f/128.f);
      float var = s2 * (1.f/128.f) - mu*mu;
      float inv = rsqrtf(fmaxf(var, 0.f) + 1e-5f);
      float4 o4;
      o4.x = softplus_f((v.x - mu)*inv*gv.x + btv.x);
      o4.y = softplus_f((v.y - mu)*inv*gv.y + btv.y);
      o4.z = softplus_f((v.z - mu)*inv*gv.z + btv.z);
      o4.w = softplus_f((v.w - mu)*inv*gv.w + btv.w);
      *(float4*)(hs + (ng*4 + nn)*128 + 4*cg) = o4;
    }
  }
  __syncthreads();

  // ---- layer 2: 128 -> 128, LN, softplus, proj -> per-node energy in es ----
  {
    float4 acc[4];
    #pragma unroll
    for (int i = 0; i < 4; i++) acc[i] = make_float4(0.f,0.f,0.f,0.f);
    const float* wp = W2 + 4*cg;
    const float* hp = hs + ng*4*128;
    float4 w[8];
    #pragma unroll
    for (int j = 0; j < 8; j++) w[j] = *(const float4*)(wp + j*128);
    for (int k = 0; k < 128; k += 8){
      float4 wn[8];
      int kn = (k + 8 < 128) ? k + 8 : 0;
      #pragma unroll
      for (int j = 0; j < 8; j++) wn[j] = *(const float4*)(wp + (kn+j)*128);
      #pragma unroll
      for (int h = 0; h < 2; h++){
        #pragma unroll
        for (int nn = 0; nn < 4; nn++){
          float4 hv = *(const float4*)(hp + nn*128 + k + h*4);
          fma4(acc[nn], hv.x, w[h*4+0]); fma4(acc[nn], hv.y, w[h*4+1]);
          fma4(acc[nn], hv.z, w[h*4+2]); fma4(acc[nn], hv.w, w[h*4+3]);
        }
      }
      #pragma unroll
      for (int j = 0; j < 8; j++) w[j] = wn[j];
    }
    float4 bv  = *(const float4*)(b2  + 4*cg);
    float4 gv  = *(const float4*)(g2  + 4*cg);
    float4 btv = *(const float4*)(bt2 + 4*cg);
    float4 wo  = *(const float4*)(Wout + 4*cg);
    #pragma unroll
    for (int nn = 0; nn < 4; nn++){
      float4 v = acc[nn];
      v.x += bv.x; v.y += bv.y; v.z += bv.z; v.w += bv.w;
      float s1 = v.x + v.y + v.z + v.w;
      float s2 = v.x*v.x + v.y*v.y + v.z*v.z + v.w*v.w;
      #pragma unroll
      for (int o = 16; o > 0; o >>= 1){ s1 += __shfl_xor(s1, o, 64); s2 += __shfl_xor(s2, o, 64); }
      float mu  = s1 * (1.f/128.f);
      float var = s2 * (1.f/128.f) - mu*mu;
      float inv = rsqrtf(fmaxf(var, 0.f) + 1e-5f);
      float ev = softplus_f((v.x - mu)*inv*gv.x + btv.x) * wo.x
               + softplus_f((v.y - mu)*inv*gv.y + btv.y) * wo.y
               + softplus_f((v.z - mu)*inv*gv.z + btv.z) * wo.z
               + softplus_f((v.w - mu)*inv*gv.w + btv.w) * wo.w;
      #pragma unroll
      for (int o = 16; o > 0; o >>= 1) ev += __shfl_xor(ev, o, 64);
      if (cg == 0) es[ng*4 + nn] = ev;
    }
  }
  __syncthreads();

  // ---- segmented reduction over the sorted 32-node tile ----
  if (t < 32){
    int node = n0 + t;
    int g = batch[node];
    bool head = (t == 0) || (batch[node-1] != g);
    if (head){
      float s = 0.f; int c = 0;
      int j = t;
      while (j < 32 && batch[n0+j] == g){ s += es[j]; c++; j++; }
      atomicAdd(&gsum[g], s);
      atomicAdd(&gcnt[g], c);
    }
  }
}

// ---------------- final ----------------
__global__ void k_final(const float* __restrict__ gsum, const int* __restrict__ gcnt,
                        const float* __restrict__ bout, float* __restrict__ out){
  int g = threadIdx.x;
  if (g < NGRAPH)
    out[g] = gsum[g] / fmaxf((float)gcnt[g], 1.f) + bout[0];
}

extern "C" void kernel_launch(void* const* d_in, const int* in_sizes, int n_in,
                              void* d_out, int out_size, void* d_ws, size_t ws_size,
                              hipStream_t stream){
  const int*   numbers = (const int*)d_in[0];
  const int*   eidx    = (const int*)d_in[1];
  const float* elen    = (const float*)d_in[2];
  const int*   batch   = (const int*)d_in[3];
  const float* embed   = (const float*)d_in[4];
  const float* Wf      = (const float*)d_in[5];
  const float* bf      = (const float*)d_in[6];
  const float* Ws      = (const float*)d_in[7];
  const float* bs      = (const float*)d_in[8];
  const float* lng     = (const float*)d_in[9];
  const float* lnb     = (const float*)d_in[10];
  const float* W1      = (const float*)d_in[11];
  const float* b1      = (const float*)d_in[12];
  const float* g1      = (const float*)d_in[13];
  const float* bt1     = (const float*)d_in[14];
  const float* W2      = (const float*)d_in[15];
  const float* b2      = (const float*)d_in[16];
  const float* g2      = (const float*)d_in[17];
  const float* bt2     = (const float*)d_in[18];
  const float* Wout    = (const float*)d_in[19];
  const float* bout    = (const float*)d_in[20];
  const int* src = eidx;
  const int* tgt = eidx + NEDGES;

  float*   x    = (float*)d_ws;                          // N*64 f32
  __half2* pqh  = (__half2*)(x + (size_t)NNODES*64);     // N*128 half2
  __half*  Gth  = (__half*)(pqh + (size_t)NNODES*128);   // 3*TBL*128 half
  float*   Wcat = (float*)(Gth + (size_t)3*TBL*128);     // 3*64*256 f32
  int2*    ep   = (int2*)(Wcat + (size_t)3*64*256);      // E int2 (final CSR)
  int2*    ebuf = ep + NEDGES;                           // E int2 (staging)
  int*     offs = (int*)(ebuf + NEDGES);                 // N+1
  int*     ccnt = offs + NNODES + 1;                     // 256
  int*     cbase= ccnt + 256;                            // 256 (197 used)
  int*     ccur = cbase + 256;                           // 256
  float*   gsum = (float*)(ccur + 256);                  // 256
  int*     gcnt = (int*)(gsum + NGRAPH);                 // 256
  float*   out  = (float*)d_out;

  k_init  <<<(NNODES+255)/256, 256, 0, stream>>>(ccnt, gsum, gcnt);
  k_embed <<<(NNODES*64+255)/256, 256, 0, stream>>>(numbers, embed, x);

  k_cnt   <<<(NEDGES+2047)/2048, 256, 0, stream>>>(src, ccnt);
  k_cscan <<<1, 256, 0, stream>>>(ccnt, cbase, ccur, offs);
  k_bin   <<<(NEDGES+2047)/2048, 256, 0, stream>>>(src, tgt, elen, ccur, ebuf);
  k_fine  <<<NCHUNK, 512, 0, stream>>>(cbase, ebuf, ep, offs);

  k_gauss <<<3*TBL, 128, 0, stream>>>(Wf, bf, Ws, bs, Gth);
  k_wcat  <<<(3*64*256+255)/256, 256, 0, stream>>>(Wf, Ws, Wcat);

  for (int i = 0; i < NCONV; i++){
    k_ntrans<<<NNODES/32, 256, 0, stream>>>(x, Wcat + (size_t)i*64*256, pqh);
    k_edge  <<<NNODES/4, 256, 0, stream>>>(pqh, offs, ep,
                                           Gth + (size_t)i*TBL*128,
                                           lng + i*64, lnb + i*64, x);
  }

  k_head<<<NNODES/32, 256, 0, stream>>>(x, W1, b1, g1, bt1,
                                        W2, b2, g2, bt2, Wout, batch, gsum, gcnt);
  k_final<<<1, 256, 0, stream>>>(gsum, gcnt, bout, out);
}